// Round 1
// baseline (138.915 us; speedup 1.0000x reference)
//
#include <hip/hip_runtime.h>
#include <math.h>

#define NTOK 100
#define EDIM 5
#define NH   4
#define NL   3
#define DD   64
#define BLK  256

// ---------------------------------------------------------------------------
// Kernel 1: fold per-head projections into 5x5 matrices.
//   M[l][h] = (1/8)*log2(e) * Wq^T Wk    (softmax then uses native exp2)
//   P[l][h] = Wv^T Wo_h^T
// ws layout: float [2][NL][NH][EDIM][8]
// ---------------------------------------------------------------------------
__global__ void precompute_mp(const float* __restrict__ Wq,
                              const float* __restrict__ Wk,
                              const float* __restrict__ Wv,
                              const float* __restrict__ Wo,
                              float* __restrict__ mp) {
  const int blk = blockIdx.x;            // 24 = which(2) * l(3) * h(4)
  const int which = blk / 12;
  const int rem = blk % 12;
  const int l = rem / 4, h = rem % 4;
  const int t = threadIdx.x;             // 64 threads

  __shared__ float A[320];               // [d*5+e]
  __shared__ float Bsh[320];             // which0: [d*5+f] ; which1: [f*64+d]

  const float* wa = (which ? Wv : Wq) + (l*NH + h)*DD*EDIM;
  for (int r = t; r < 320; r += 64) A[r] = wa[r];
  if (which == 0) {
    const float* wk = Wk + (l*NH + h)*DD*EDIM;
    for (int r = t; r < 320; r += 64) Bsh[r] = wk[r];
  } else {
    for (int r = t; r < 320; r += 64) {
      int f = r >> 6, d = r & 63;
      Bsh[r] = Wo[(l*EDIM + f)*(NH*DD) + h*DD + d];
    }
  }
  __syncthreads();
  if (t < 25) {
    int e = t / 5, f = t % 5;
    float acc = 0.f;
    if (which == 0) {
      #pragma unroll 8
      for (int d = 0; d < DD; ++d) acc += A[d*5+e] * Bsh[d*5+f];
      acc *= 0.125f * 1.44269504088896340736f;   // fold log2(e) -> exp2 softmax
    } else {
      #pragma unroll 8
      for (int d = 0; d < DD; ++d) acc += A[d*5+e] * Bsh[f*64+d];
    }
    mp[which*960 + ((l*NH + h)*EDIM + e)*8 + f] = acc;
  }
}

// ---------------------------------------------------------------------------
// Kernel 2: one workgroup per batch.  Restructured for wave density:
//   wave w == head w; lane i == attention row i (1 row/lane; uniform 2-pass
//   loop covers the rare nm>=64 case).
//   Each wave keeps a PRIVATE copy of the token state o in LDS, so the
//   attention j-loop (broadcast reads) and the token update are intra-wave.
//   P is applied inside the attention threads (wp = (w+rep_corr)*inv @ P_h),
//   so the only cross-wave traffic is wp[5]/head -> ONE barrier per layer
//   (wp double-buffered by layer parity; hazard-free via barrier rendezvous).
//   Rep row: a[] zeroed so exp2(0)=1 gives the uniform-row weights without a
//   per-iteration select; correction w += (100-nm)*o_rep, inv = 1/100.
// ---------------------------------------------------------------------------
__global__ __launch_bounds__(BLK, 4) void encoder_kernel(
    const float* __restrict__ x,
    const float* __restrict__ mp,
    const float* __restrict__ Wf,
    const float* __restrict__ bfv,
    const float* __restrict__ g1,
    const float* __restrict__ b1,
    const float* __restrict__ g2,
    const float* __restrict__ b2,
    float* __restrict__ out)
{
  const int b = blockIdx.x, t = threadIdx.x;
  const int wv = t >> 6;        // wave id == head id
  const int ln = t & 63;        // lane

  __shared__ float4 s_MP4[480];                 // 1920 floats: M then P
  __shared__ float4 s_o4[NH][NTOK+2];           // per-wave token state [0..3]
  __shared__ float  s_o1[NH][NTOK+2];           // per-wave token state [4]
  __shared__ float4 s_wp4[2][NH][NTOK+2];       // P-applied head outputs [0..3]
  __shared__ float  s_wp1[2][NH][NTOK+2];       // [4]  (dbuf by layer parity)
  __shared__ int    s_cidx[NTOK];
  __shared__ unsigned long long s_bal[2];

  const float* mpf = (const float*)s_MP4;
  for (int r = t; r < 480; r += BLK) s_MP4[r] = ((const float4*)mp)[r];

  // ---- setup: mask + ballot-based compaction ----
  float k0=0.f, k1=0.f, k2=0.f, msk=0.f;
  if (t < NTOK) {
    k0 = x[b*300 + 3*t];
    k1 = x[b*300 + 3*t + 1];
    k2 = x[b*300 + 3*t + 2];
    msk = (k2 > 0.f) ? 1.f : 0.f;
  }
  unsigned long long bal = __ballot(t < NTOK && msk != 0.f);
  if (t == 0)  s_bal[0] = bal;
  if (t == 64) s_bal[1] = bal;
  __syncthreads();
  const unsigned long long bw0 = s_bal[0], bw1 = s_bal[1];
  const int nm = __popcll(bw0) + __popcll(bw1);   // # unmasked tokens
  if (t < NTOK) {
    int lane = t & 63;
    unsigned long long lm = (lane == 0) ? 0ull : ((1ull << lane) - 1ull);
    int pre = (t < 64) ? __popcll(bw0 & lm) : (__popcll(bw0) + __popcll(bw1 & lm));
    if (msk != 0.f) {
      float4 v = make_float4(k0, k1, k2, sinf((float)t));
      float v4 = cosf((float)t);
      #pragma unroll
      for (int w = 0; w < NH; ++w) { s_o4[w][pre] = v; s_o1[w][pre] = v4; }
      s_cidx[t] = pre;
    } else {
      s_cidx[t] = nm;
    }
  }
  if (t == 0) {
    #pragma unroll
    for (int w = 0; w < NH; ++w) {
      s_o4[w][nm] = make_float4(0.f,0.f,0.f,0.f);   // rep token
      s_o1[w][nm] = 0.f;
    }
  }
  __syncthreads();

  const int rows = nm + 1;                   // rows include the rep token
  const int npass = (rows > 64) ? 2 : 1;     // uniform per block
  const float4* ow4 = s_o4[wv];
  const float*  ow1 = s_o1[wv];
  int bufp = 0;

  for (int l = 0; l < NL; ++l) {
    const float* Mh = mpf + ((l*NH + wv)*EDIM)*8;
    const float* Ph = mpf + 960 + ((l*NH + wv)*EDIM)*8;

    // ---- attention + P-apply: 4 dense waves, wave-local state ----
    for (int ps = 0; ps < npass; ++ps) {
      const int i = ln + (ps << 6);
      if (i < rows) {
        const bool rep = (i == nm);
        float4 ov = ow4[i]; float ov4 = ow1[i];
        float o_[5] = {ov.x, ov.y, ov.z, ov.w, ov4};
        float a0=0.f,a1=0.f,a2=0.f,a3=0.f,a4=0.f;
        #pragma unroll
        for (int e = 0; e < 5; ++e) {
          float4 mr = *(const float4*)(Mh + e*8); float m4 = Mh[e*8+4];
          a0 += o_[e]*mr.x; a1 += o_[e]*mr.y; a2 += o_[e]*mr.z;
          a3 += o_[e]*mr.w; a4 += o_[e]*m4;
        }
        if (rep) { a0=0.f; a1=0.f; a2=0.f; a3=0.f; a4=0.f; }  // exp2(0)=1

        float w0=0.f,w1=0.f,w2=0.f,w3=0.f,w4=0.f, ls=0.f;
        #pragma unroll 4
        for (int j = 0; j < nm; ++j) {
          float4 oj = ow4[j]; float oe = ow1[j];      // wave-private broadcast
          float s = a0*oj.x + a1*oj.y + a2*oj.z + a3*oj.w + a4*oe;
          float p = exp2f(s);                          // native v_exp_f32
          ls += p;
          w0 += p*oj.x; w1 += p*oj.y; w2 += p*oj.z; w3 += p*oj.w; w4 += p*oe;
        }
        if (rep) {
          // uniform 1/100 row also averages (100-nm) masked tokens = rep state
          float wext = (float)(NTOK - nm);
          w0 += wext*o_[0]; w1 += wext*o_[1]; w2 += wext*o_[2];
          w3 += wext*o_[3]; w4 += wext*o_[4];
        }
        float inv = 1.f / (rep ? (float)NTOK : ls);
        float we[5] = {w0,w1,w2,w3,w4};
        float c0=0.f,c1=0.f,c2=0.f,c3=0.f,c4=0.f;
        #pragma unroll
        for (int e = 0; e < 5; ++e) {
          float4 pr = *(const float4*)(Ph + e*8); float p4 = Ph[e*8+4];
          c0 += we[e]*pr.x; c1 += we[e]*pr.y; c2 += we[e]*pr.z;
          c3 += we[e]*pr.w; c4 += we[e]*p4;
        }
        s_wp4[bufp][wv][i] = make_float4(c0*inv, c1*inv, c2*inv, c3*inv);
        s_wp1[bufp][wv][i] = c4*inv;
      }
    }
    __syncthreads();   // the ONLY barrier per layer: wp exchange

    // ---- token update: redundant per wave (keeps state wave-private) ----
    for (int ps = 0; ps < npass; ++ps) {
      const int i = ln + (ps << 6);
      if (i < rows) {
        float4 ov = ow4[i]; float ov4 = ow1[i];
        float y[5] = {ov.x, ov.y, ov.z, ov.w, ov4};
        #pragma unroll
        for (int hh = 0; hh < NH; ++hh) {
          float4 wa = s_wp4[bufp][hh][i];
          y[0] += wa.x; y[1] += wa.y; y[2] += wa.z; y[3] += wa.w;
          y[4] += s_wp1[bufp][hh][i];
        }
        float mu = 0.2f*(y[0]+y[1]+y[2]+y[3]+y[4]);
        float var = 0.f;
        #pragma unroll
        for (int e = 0; e < 5; ++e) { float d = y[e]-mu; var += d*d; }
        var *= 0.2f;
        float inv1 = 1.f / sqrtf(var + 1e-5f);
        float ln1[5];
        #pragma unroll
        for (int e = 0; e < 5; ++e) ln1[e] = (y[e]-mu)*inv1*g1[l*5+e] + b1[l*5+e];
        float r2[5];
        #pragma unroll
        for (int e = 0; e < 5; ++e) {
          float acc = bfv[l*5+e];
          #pragma unroll
          for (int f = 0; f < 5; ++f) acc += ln1[f]*Wf[(l*5+e)*5+f];
          acc = acc > 0.f ? acc : 0.f;
          r2[e] = acc + ln1[e];
        }
        float mu2 = 0.2f*(r2[0]+r2[1]+r2[2]+r2[3]+r2[4]);
        float var2 = 0.f;
        #pragma unroll
        for (int e = 0; e < 5; ++e) { float d = r2[e]-mu2; var2 += d*d; }
        var2 *= 0.2f;
        float inv2 = 1.f / sqrtf(var2 + 1e-5f);
        float no[5];
        #pragma unroll
        for (int e = 0; e < 5; ++e) no[e] = (r2[e]-mu2)*inv2*g2[l*5+e] + b2[l*5+e];
        s_o4[wv][i] = make_float4(no[0], no[1], no[2], no[3]);
        s_o1[wv][i] = no[4];
        // no barrier needed here: next layer's reads of o are intra-wave;
        // wp hazards are covered by the per-layer barrier + parity dbuf.
      }
    }
    bufp ^= 1;
  }
  __syncthreads();   // wave 0's copy -> all threads for the store

  // ---- expand compacted state back to [N, E] ----
  for (int r = t; r < NTOK*EDIM; r += BLK) {
    int i = r / EDIM;
    int e = r - i*EDIM;
    int c = s_cidx[i];
    float v = (e < 4) ? ((const float*)&s_o4[0][c])[e] : s_o1[0][c];
    out[b*(NTOK*EDIM) + r] = v;
  }
}

extern "C" void kernel_launch(void* const* d_in, const int* in_sizes, int n_in,
                              void* d_out, int out_size, void* d_ws, size_t ws_size,
                              hipStream_t stream) {
  const float* x  = (const float*)d_in[0];
  const float* Wq = (const float*)d_in[1];
  const float* Wk = (const float*)d_in[2];
  const float* Wv = (const float*)d_in[3];
  const float* Wo = (const float*)d_in[4];
  const float* Wf = (const float*)d_in[5];
  const float* bf = (const float*)d_in[6];
  const float* g1 = (const float*)d_in[7];
  const float* b1 = (const float*)d_in[8];
  const float* g2 = (const float*)d_in[9];
  const float* b2 = (const float*)d_in[10];
  float* outp = (float*)d_out;
  float* mp   = (float*)d_ws;   // 1920 floats

  precompute_mp<<<24, 64, 0, stream>>>(Wq, Wk, Wv, Wo, mp);
  encoder_kernel<<<1024, BLK, 0, stream>>>(x, mp, Wf, bf, g1, b1, g2, b2, outp);
}